// Round 8
// baseline (365.748 us; speedup 1.0000x reference)
//
#include <hip/hip_runtime.h>
#include <hip/hip_bf16.h>
#include <math.h>

#define D_MODEL 768
#define NH 16
#define DH 48
#define NP 4
#define LQ 4096
#define BB 2
#define MTOT (BB * LQ)  // 8192

typedef __attribute__((ext_vector_type(8))) _Float16 half8_t;
typedef __attribute__((ext_vector_type(4))) float floatx4;

__device__ __forceinline__ void load_lds16(const void* g, void* l) {
    __builtin_amdgcn_global_load_lds((const __attribute__((address_space(1))) void*)g,
                                     (__attribute__((address_space(3))) void*)l, 16, 0, 0);
}

// ---------------------------------------------------------------------------
// fp16 MFMA GEMM tile body, 3-buffer pipeline with COUNTED vmcnt (T4):
//   prologue: stage(0), stage(1)
//   iter t:   stage(t+2); waitcnt(8|4|0); s_barrier; compute(t); s_barrier
// Loads stay in flight ACROSS barriers (never drained to 0 mid-loop).
// Each thread issues exactly 4 global_load_lds per stage -> waits are exact.
// A: (M x 768 fp16); Wt: (ldc x 768 fp16, transposed). 128x128 tile, BK=32,
// 4 waves (2x2), 4x4 16x16x32 MFMA per wave.
// MODE 0: fp32 C = acc + bias               (offc)
// MODE 1: fp32 C = gamma*(attn16 + acc + b) (final)
// MODE 2: fp16 C = acc + bias               (qn/fn raw, val, attn)
// ---------------------------------------------------------------------------
template <int MODE>
__device__ __forceinline__ void gemm_body(
    const _Float16* __restrict__ A, const _Float16* __restrict__ Wt,
    const float* __restrict__ bias, void* __restrict__ Cv, int ldc,
    int tm, int tn,
    const _Float16* __restrict__ attn, const float* __restrict__ gamma)
{
    constexpr int K = 768;
    constexpr int NT = K / 32;  // 24 K-steps
    __shared__ _Float16 As[3][128 * 32];
    __shared__ _Float16 Bs[3][128 * 32];

    const int bm = tm * 128, bn = tn * 128;
    const int t = threadIdx.x;
    const int lane = t & 63;
    const int w = t >> 6;
    const int wm = (w >> 1) * 64, wn = (w & 1) * 64;

    floatx4 acc[4][4] = {};

    const int r0 = t >> 2;
    const int c8 = (t & 3) * 8;
    const size_t arow0 = (size_t)(bm + r0) * K + c8;
    const size_t arow1 = (size_t)(bm + 64 + r0) * K + c8;
    const size_t brow0 = (size_t)(bn + r0) * K + c8;
    const size_t brow1 = (size_t)(bn + 64 + r0) * K + c8;

    const int lrow = lane & 15;
    const int lk = (lane >> 4) * 8;

    auto STAGE = [&](int step) {
        const int b3 = step % 3;
        const size_t kn = (size_t)step * 32;
        _Float16* asb = &As[b3][0];
        _Float16* bsb = &Bs[b3][0];
        load_lds16(A + arow0 + kn, asb + w * 512);
        load_lds16(A + arow1 + kn, asb + 2048 + w * 512);
        load_lds16(Wt + brow0 + kn, bsb + w * 512);
        load_lds16(Wt + brow1 + kn, bsb + 2048 + w * 512);
    };

    STAGE(0);
    STAGE(1);

    for (int ti = 0; ti < NT; ++ti) {
        const int cur = ti % 3;
        if (ti + 2 < NT) STAGE(ti + 2);

        // wait for stage(ti) only; later stages stay in flight across the barrier
        if (ti < NT - 2)       asm volatile("s_waitcnt vmcnt(8)" ::: "memory");
        else if (ti == NT - 2) asm volatile("s_waitcnt vmcnt(4)" ::: "memory");
        else                   asm volatile("s_waitcnt vmcnt(0)" ::: "memory");
        __builtin_amdgcn_s_barrier();
        __builtin_amdgcn_sched_barrier(0);  // keep ds_reads below the barrier

        const _Float16* Ac = &As[cur][0];
        const _Float16* Bc = &Bs[cur][0];
        half8_t af[4], bf[4];
#pragma unroll
        for (int i = 0; i < 4; ++i) {
            af[i] = *(const half8_t*)&Ac[(wm + i * 16 + lrow) * 32 + lk];
            bf[i] = *(const half8_t*)&Bc[(wn + i * 16 + lrow) * 32 + lk];
        }
#pragma unroll
        for (int i = 0; i < 4; ++i)
#pragma unroll
            for (int j = 0; j < 4; ++j)
                acc[i][j] = __builtin_amdgcn_mfma_f32_16x16x32_f16(af[i], bf[j], acc[i][j], 0, 0, 0);

        __builtin_amdgcn_sched_barrier(0);  // keep ds_reads above this barrier
        __builtin_amdgcn_s_barrier();       // all waves done reading buf before reuse
    }

    // epilogue: C/D layout col=lane&15, row=(lane>>4)*4+reg
    const int rquad = (lane >> 4) * 4;
#pragma unroll
    for (int i = 0; i < 4; ++i) {
#pragma unroll
        for (int j = 0; j < 4; ++j) {
            const int col = bn + wn + j * 16 + lrow;
            const float bcol = bias[col];
#pragma unroll
            for (int r = 0; r < 4; ++r) {
                const size_t row = (size_t)(bm + wm + i * 16 + rquad + r);
                float v = acc[i][j][r] + bcol;
                if constexpr (MODE == 1) {
                    v = ((float)attn[row * (size_t)ldc + col] + v) * gamma[col];
                    ((float*)Cv)[row * (size_t)ldc + col] = v;
                } else if constexpr (MODE == 2) {
                    ((_Float16*)Cv)[row * (size_t)ldc + col] = (_Float16)v;
                } else {
                    ((float*)Cv)[row * (size_t)ldc + col] = v;
                }
            }
        }
    }
}

// Single GEMM: N=768 (6 col tiles), 384 blocks, XCD-swizzled.
template <int MODE>
__global__ __launch_bounds__(256) void gemm_mfma(
    const _Float16* __restrict__ A, const _Float16* __restrict__ Wt,
    const float* __restrict__ bias, void* __restrict__ C,
    const _Float16* __restrict__ attn, const float* __restrict__ gamma)
{
    const int bid = blockIdx.x;
    const int swz = (bid & 7) * 48 + (bid >> 3);
    gemm_body<MODE>(A, Wt, bias, C, 768, swz & 63, swz >> 6, attn, gamma);
}

// Dual GEMM: two independent jobs, per-job output mode. Counts divisible by 8.
template <int M0, int M1>
__global__ __launch_bounds__(256) void dual_gemm(
    const _Float16* __restrict__ A0, const _Float16* __restrict__ W0,
    const float* __restrict__ b0, void* __restrict__ C0, int ldc0, int cnt0,
    const _Float16* __restrict__ A1, const _Float16* __restrict__ W1,
    const float* __restrict__ b1, void* __restrict__ C1, int ldc1, int cnt1)
{
    int bid = blockIdx.x;
    if (bid < cnt0) {
        const int q = cnt0 >> 3;
        const int swz = (bid & 7) * q + (bid >> 3);
        gemm_body<M0>(A0, W0, b0, C0, ldc0, swz & 63, swz >> 6, nullptr, nullptr);
    } else {
        bid -= cnt0;
        const int q = cnt1 >> 3;
        const int swz = (bid & 7) * q + (bid >> 3);
        gemm_body<M1>(A1, W1, b1, C1, ldc1, swz & 63, swz >> 6, nullptr, nullptr);
    }
}

// ---------------------------------------------------------------------------
// LayerNorm, wave-per-row, fp16 in -> fp16 out. In-place safe (reads complete
// before writes within the owning wave; rows are wave-exclusive).
// ---------------------------------------------------------------------------
__device__ __forceinline__ void ln_wave_body(
    const _Float16* __restrict__ X, _Float16* __restrict__ A,
    const float* __restrict__ g, const float* __restrict__ beta, int row)
{
    const int lane = threadIdx.x & 63;
    const _Float16* x = X + (size_t)row * D_MODEL;
    float v[12];
    float s = 0.f, s2 = 0.f;
#pragma unroll
    for (int j = 0; j < 12; ++j) {
        v[j] = (float)x[lane + 64 * j];
        s += v[j];
        s2 += v[j] * v[j];
    }
#pragma unroll
    for (int m = 1; m < 64; m <<= 1) {
        s += __shfl_xor(s, m);
        s2 += __shfl_xor(s2, m);
    }
    const float mean = s * (1.f / 768.f);
    const float var = s2 * (1.f / 768.f) - mean * mean;
    const float rstd = rsqrtf(var + 1e-6f);
    _Float16* arow = A + (size_t)row * D_MODEL;
#pragma unroll
    for (int j = 0; j < 12; ++j) {
        const int cc = lane + 64 * j;
        arow[cc] = (_Float16)((v[j] - mean) * rstd * g[cc] + beta[cc]);
    }
}

__global__ __launch_bounds__(256) void ln2_wave(
    const _Float16* __restrict__ X0, _Float16* __restrict__ A0,
    const float* __restrict__ g0, const float* __restrict__ b0,
    const _Float16* __restrict__ X1, _Float16* __restrict__ A1,
    const float* __restrict__ g1, const float* __restrict__ b1)
{
    const int r = blockIdx.x * 4 + (threadIdx.x >> 6);
    if (r < MTOT) ln_wave_body(X0, A0, g0, b0, r);
    else          ln_wave_body(X1, A1, g1, b1, r - MTOT);
}

__global__ __launch_bounds__(256) void ln_wave(
    const _Float16* __restrict__ X, _Float16* __restrict__ A,
    const float* __restrict__ g, const float* __restrict__ beta)
{
    const int r = blockIdx.x * 4 + (threadIdx.x >> 6);
    ln_wave_body(X, A, g, beta, r);
}

// ---------------------------------------------------------------------------
// Merged conversions: [0,12288) act fp32->fp16; [12288,15744) weight transpose
// fp32->fp16; [15744,16128) combined offset|aw weights + bias.
// ---------------------------------------------------------------------------
__global__ __launch_bounds__(256) void convert_all(
    const float* __restrict__ query, _Float16* __restrict__ actA,
    const float* __restrict__ feat, _Float16* __restrict__ actB,
    const float* __restrict__ w0, const float* __restrict__ w1,
    const float* __restrict__ w2, const float* __restrict__ w3,
    const float* __restrict__ w4, const float* __restrict__ w5,
    _Float16* __restrict__ Wall,
    const float* __restrict__ Woff_c, const float* __restrict__ Wa_c,
    const float* __restrict__ boff_c, const float* __restrict__ ba_c,
    const float* __restrict__ Woff_s, const float* __restrict__ Wa_s,
    const float* __restrict__ boff_s, const float* __restrict__ ba_s,
    _Float16* __restrict__ Wc, _Float16* __restrict__ Ws,
    float* __restrict__ bias_c, float* __restrict__ bias_s)
{
    __shared__ float tile[32][33];
    const int bid = blockIdx.x;
    const int t = threadIdx.x;

    if (bid < 12288) {
        const int i = bid * 256 + t;
        const int sel = i / (MTOT * 192);
        const int r = i - sel * (MTOT * 192);
        const float* X = sel ? feat : query;
        _Float16* D = sel ? actB : actA;
        const int c4 = r * 4;
        const float4 v = *(const float4*)(X + (size_t)c4);
        _Float16 o[4] = {(_Float16)v.x, (_Float16)v.y, (_Float16)v.z, (_Float16)v.w};
        *(uint2*)(D + (size_t)c4) = *(uint2*)o;
    } else if (bid < 15744) {
        const int g = bid - 12288;
        const int wi = g / 576;
        const int gx = g - wi * 576;
        const float* W = (wi == 0) ? w0 : (wi == 1) ? w1 : (wi == 2) ? w2
                       : (wi == 3) ? w3 : (wi == 4) ? w4 : w5;
        _Float16* Wt = Wall + (size_t)wi * 768 * 768;
        const int tk0 = (gx / 24) * 32;
        const int tn0 = (gx % 24) * 32;
#pragma unroll
        for (int r = 0; r < 4; ++r) {
            const int row = r * 8 + (t >> 5);
            const int col = t & 31;
            tile[row][col] = W[(size_t)(tk0 + row) * 768 + tn0 + col];
        }
        __syncthreads();
        const int n = t >> 3;
        const int kq = (t & 7) * 4;
        _Float16* dst = Wt + (size_t)(tn0 + n) * 768 + tk0 + kq;
#pragma unroll
        for (int u = 0; u < 4; ++u) dst[u] = (_Float16)tile[kq + u][n];
    } else {
        const int i = (bid - 15744) * 256 + t;
        if (i >= 2 * 256 * 192) return;
        const int pair = i / (256 * 192);
        const int r = i - pair * (256 * 192);
        const int n = r / 192;
        const int k0 = (r - n * 192) * 4;
        const float* Woff = pair ? Woff_s : Woff_c;
        const float* Wa = pair ? Wa_s : Wa_c;
        _Float16* dst = pair ? Ws : Wc;
        _Float16* row = dst + (size_t)n * 768;
#pragma unroll
        for (int u = 0; u < 4; ++u) {
            const int k = k0 + u;
            float v = (n < 128) ? Woff[(size_t)k * 128 + n]
                    : (n < 192) ? Wa[(size_t)k * 64 + (n - 128)] : 0.f;
            row[k] = (_Float16)v;
        }
        if (k0 == 0) {
            const float* boff = pair ? boff_s : boff_c;
            const float* ba = pair ? ba_s : ba_c;
            float* bias = pair ? bias_s : bias_c;
            bias[n] = (n < 128) ? boff[n] : (n < 192) ? ba[n - 128] : 0.f;
        }
    }
}

// ---------------------------------------------------------------------------
// Fused softmax/loc + bilinear sampling. 192-thread blocks, each covers 2 bq.
// Threads 0..31 compute loc/aw for the block's 32 (bq,h) into LDS; then all
// 192 threads sample: thread -> (lbqh = tid/6, c = tid%6), d0 = 8c, fp16 val.
// XCD-chunk swizzle over 4096 blocks.
// ---------------------------------------------------------------------------
__global__ __launch_bounds__(192) void sample_fused(
    const _Float16* __restrict__ value, const float* __restrict__ offc,
    _Float16* __restrict__ A)
{
    __shared__ float loc_s[32][8];
    __shared__ float aw_s[32][4];

    const int bid = blockIdx.x;                    // 4096 = 8 * 512
    const int swz = (bid & 7) * 512 + (bid >> 3);  // XCD-chunk swizzle
    const int bq_base = swz * 2;
    const int t = threadIdx.x;

    if (t < 32) {
        const int bq = bq_base + (t >> 4);
        const int h = t & 15;
        const int q = bq & (LQ - 1);
        const float* orow = offc + (size_t)bq * 256 + h * 8;
        const float* arow = offc + (size_t)bq * 256 + 128 + h * 4;
        float a0 = arow[0], a1 = arow[1], a2 = arow[2], a3 = arow[3];
        float mx = fmaxf(fmaxf(a0, a1), fmaxf(a2, a3));
        float e0 = expf(a0 - mx), e1 = expf(a1 - mx), e2 = expf(a2 - mx), e3 = expf(a3 - mx);
        float r = 1.f / (e0 + e1 + e2 + e3);
        const float refx = ((q & 63) + 0.5f) * (1.f / 64.f);
        const float refy = ((q >> 6) + 0.5f) * (1.f / 64.f);
#pragma unroll
        for (int p = 0; p < 4; ++p) {
            loc_s[t][p * 2 + 0] = refx + orow[p * 2 + 0] * (1.f / 64.f);
            loc_s[t][p * 2 + 1] = refy + orow[p * 2 + 1] * (1.f / 64.f);
        }
        aw_s[t][0] = e0 * r; aw_s[t][1] = e1 * r;
        aw_s[t][2] = e2 * r; aw_s[t][3] = e3 * r;
    }
    __syncthreads();

    const int lbqh = t / 6;
    const int c = t - lbqh * 6;
    const int d0 = c * 8;
    const int bq = bq_base + (lbqh >> 4);
    const int h = lbqh & 15;
    const int b = bq >> 12;

    const _Float16* vbase = value + (size_t)b * LQ * D_MODEL + h * DH + d0;

    float acc[8] = {};
#pragma unroll
    for (int p = 0; p < 4; ++p) {
        const float x = loc_s[lbqh][p * 2 + 0] * 64.f - 0.5f;
        const float y = loc_s[lbqh][p * 2 + 1] * 64.f - 0.5f;
        const float xf = floorf(x), yf = floorf(y);
        const float wx1 = x - xf, wy1 = y - yf;
        const float wx0 = 1.f - wx1, wy0 = 1.f - wy1;
        const int x0 = (int)xf, y0 = (int)yf;
        const int x1 = x0 + 1, y1 = y0 + 1;
        const float wp = aw_s[lbqh][p];
        const bool vx0 = (x0 >= 0) && (x0 < 64);
        const bool vx1 = (x1 >= 0) && (x1 < 64);
        const bool vy0 = (y0 >= 0) && (y0 < 64);
        const bool vy1 = (y1 >= 0) && (y1 < 64);
        const float cw[4] = {wp * wx0 * wy0, wp * wx1 * wy0, wp * wx0 * wy1, wp * wx1 * wy1};
        const bool cv[4] = {vx0 && vy0, vx1 && vy0, vx0 && vy1, vx1 && vy1};
        const int cxy[4][2] = {{x0, y0}, {x1, y0}, {x0, y1}, {x1, y1}};
#pragma unroll
        for (int k = 0; k < 4; ++k) {
            if (cv[k]) {
                const half8_t g = *(const half8_t*)(vbase + (size_t)(cxy[k][1] * 64 + cxy[k][0]) * D_MODEL);
#pragma unroll
                for (int u = 0; u < 8; ++u) acc[u] += cw[k] * (float)g[u];
            }
        }
    }

    _Float16* arow = A + (size_t)bq * D_MODEL + h * DH + d0;
    _Float16 o[8];
#pragma unroll
    for (int u = 0; u < 8; ++u) o[u] = (_Float16)acc[u];
    *(uint4*)arow = *(uint4*)o;
}

// ---------------------------------------------------------------------------
extern "C" void kernel_launch(void* const* d_in, const int* in_sizes, int n_in,
                              void* d_out, int out_size, void* d_ws, size_t ws_size,
                              hipStream_t stream)
{
    const float* query   = (const float*)d_in[0];
    const float* feat    = (const float*)d_in[1];
    const float* qn_W    = (const float*)d_in[4];
    const float* qn_b    = (const float*)d_in[5];
    const float* qn_g    = (const float*)d_in[6];
    const float* qn_beta = (const float*)d_in[7];
    const float* fn_W    = (const float*)d_in[8];
    const float* fn_b    = (const float*)d_in[9];
    const float* fn_g    = (const float*)d_in[10];
    const float* fn_beta = (const float*)d_in[11];
    const float* nm_g    = (const float*)d_in[12];
    const float* nm_beta = (const float*)d_in[13];
    const float* gamma1  = (const float*)d_in[14];
    const float* c_Wv    = (const float*)d_in[15];
    const float* c_bv    = (const float*)d_in[16];
    const float* c_Woff  = (const float*)d_in[17];
    const float* c_boff  = (const float*)d_in[18];
    const float* c_Wa    = (const float*)d_in[19];
    const float* c_ba    = (const float*)d_in[20];
    const float* c_Wo    = (const float*)d_in[21];
    const float* c_bo    = (const float*)d_in[22];
    const float* s_Wv    = (const float*)d_in[23];
    const float* s_bv    = (const float*)d_in[24];
    const float* s_Woff  = (const float*)d_in[25];
    const float* s_boff  = (const float*)d_in[26];
    const float* s_Wa    = (const float*)d_in[27];
    const float* s_ba    = (const float*)d_in[28];
    const float* s_Wo    = (const float*)d_in[29];
    const float* s_bo    = (const float*)d_in[30];

    const size_t SZ = (size_t)MTOT * D_MODEL;  // 6291456 elements
    _Float16* hA    = (_Float16*)d_ws;         // query16 -> attn16
    _Float16* hB    = hA + SZ;                 // feat16 -> samp16
    _Float16* hQ    = hB + SZ;                 // qn_raw->qn16 -> attn1n16
    _Float16* hF    = hQ + SZ;                 // fn_raw->fn16
    _Float16* val16 = hF + SZ;                 // value fp16
    float* offc   = (float*)(val16 + SZ);      // M x 256 fp32
    float* bias_c = offc + (size_t)MTOT * 256;
    float* bias_s = bias_c + 256;
    _Float16* W6 = (_Float16*)(bias_s + 256);  // 6 x 768 x 768 fp16
    _Float16* W_qn  = W6 + (size_t)0 * 768 * 768;
    _Float16* W_fn  = W6 + (size_t)1 * 768 * 768;
    _Float16* W_cWv = W6 + (size_t)2 * 768 * 768;
    _Float16* W_cWo = W6 + (size_t)3 * 768 * 768;
    _Float16* W_sWv = W6 + (size_t)4 * 768 * 768;
    _Float16* W_sWo = W6 + (size_t)5 * 768 * 768;
    _Float16* Woffa_c = W6 + (size_t)6 * 768 * 768;  // 256 x 768
    _Float16* Woffa_s = Woffa_c + (size_t)256 * 768;

    float* out = (float*)d_out;
    const dim3 blk(256);

    // ---- all conversions in one dispatch ----
    convert_all<<<16128, blk, 0, stream>>>(
        query, hA, feat, hB,
        qn_W, fn_W, c_Wv, c_Wo, s_Wv, s_Wo, W6,
        c_Woff, c_Wa, c_boff, c_ba, s_Woff, s_Wa, s_boff, s_ba,
        Woffa_c, Woffa_s, bias_c, bias_s);

    // ---- cross attention ----
    dual_gemm<2, 2><<<768, blk, 0, stream>>>(hA, W_qn, qn_b, hQ, 768, 384,
                                             hB, W_fn, fn_b, hF, 768, 384);
    ln2_wave<<<2 * MTOT / 4, blk, 0, stream>>>(hQ, hQ, qn_g, qn_beta,
                                               hF, hF, fn_g, fn_beta);
    dual_gemm<2, 0><<<512, blk, 0, stream>>>(hF, W_cWv, c_bv, val16, 768, 384,
                                             hQ, Woffa_c, bias_c, offc, 256, 128);
    sample_fused<<<4096, dim3(192), 0, stream>>>(val16, offc, hB);
    gemm_mfma<2><<<384, blk, 0, stream>>>(hB, W_cWo, c_bo, hA, nullptr, nullptr);  // attn16 -> hA

    // ---- self attention ----
    ln_wave<<<MTOT / 4, blk, 0, stream>>>(hA, hQ, nm_g, nm_beta);  // attn1 -> hQ
    dual_gemm<2, 0><<<512, blk, 0, stream>>>(hQ, W_sWv, s_bv, val16, 768, 384,
                                             hQ, Woffa_s, bias_s, offc, 256, 128);
    sample_fused<<<4096, dim3(192), 0, stream>>>(val16, offc, hB);
    // final: out = gamma1 * (attn16 + samp@s_Wo + s_bo)
    gemm_mfma<1><<<384, blk, 0, stream>>>(hB, W_sWo, s_bo, out, hA, gamma1);
}

// Round 10
// 346.191 us; speedup vs baseline: 1.0565x; 1.0565x over previous
//
#include <hip/hip_runtime.h>
#include <hip/hip_bf16.h>
#include <math.h>

#define D_MODEL 768
#define NH 16
#define DH 48
#define NP 4
#define LQ 4096
#define BB 2
#define MTOT (BB * LQ)  // 8192

typedef __attribute__((ext_vector_type(8))) _Float16 half8_t;
typedef __attribute__((ext_vector_type(4))) float floatx4;

__device__ __forceinline__ void load_lds16(const void* g, void* l) {
    __builtin_amdgcn_global_load_lds((const __attribute__((address_space(1))) void*)g,
                                     (__attribute__((address_space(3))) void*)l, 16, 0, 0);
}

// ---------------------------------------------------------------------------
// fp16 MFMA GEMM tile body, 2-phase double-buffered (proven 32 KB / high-occ
// structure): STAGE(next) issued BEFORE compute(cur); ONE __syncthreads per
// K-step. A: (M x 768 fp16); Wt: (ldc x 768 fp16, transposed). 128x128 tile,
// BK=32, 4 waves (2x2), 4x4 16x16x32 MFMA per wave.
// MODE 0: fp32 C = acc + bias               (offc)
// MODE 1: fp32 C = gamma*(attn16 + acc + b) (final)
// MODE 2: fp16 C = acc + bias               (qn/fn raw, val, attn)
// ---------------------------------------------------------------------------
template <int MODE>
__device__ __forceinline__ void gemm_body(
    const _Float16* __restrict__ A, const _Float16* __restrict__ Wt,
    const float* __restrict__ bias, void* __restrict__ Cv, int ldc,
    int tm, int tn,
    const _Float16* __restrict__ attn, const float* __restrict__ gamma)
{
    constexpr int K = 768;
    constexpr int NT = K / 32;  // 24 K-steps
    __shared__ _Float16 As[2][128 * 32];   // 2 x 8 KB
    __shared__ _Float16 Bs[2][128 * 32];   // 2 x 8 KB

    const int bm = tm * 128, bn = tn * 128;
    const int t = threadIdx.x;
    const int lane = t & 63;
    const int w = t >> 6;
    const int wm = (w >> 1) * 64, wn = (w & 1) * 64;

    floatx4 acc[4][4] = {};

    const int r0 = t >> 2;
    const int c8 = (t & 3) * 8;
    const size_t arow0 = (size_t)(bm + r0) * K + c8;
    const size_t arow1 = (size_t)(bm + 64 + r0) * K + c8;
    const size_t brow0 = (size_t)(bn + r0) * K + c8;
    const size_t brow1 = (size_t)(bn + 64 + r0) * K + c8;

    const int lrow = lane & 15;
    const int lk = (lane >> 4) * 8;

    load_lds16(A + arow0, &As[0][w * 512]);
    load_lds16(A + arow1, &As[0][2048 + w * 512]);
    load_lds16(Wt + brow0, &Bs[0][w * 512]);
    load_lds16(Wt + brow1, &Bs[0][2048 + w * 512]);
    __syncthreads();

    for (int ti = 0; ti < NT; ++ti) {
        const int cur = ti & 1;
        if (ti + 1 < NT) {
            const int kn = (ti + 1) * 32;
            const int nxt = cur ^ 1;
            load_lds16(A + arow0 + kn, &As[nxt][w * 512]);
            load_lds16(A + arow1 + kn, &As[nxt][2048 + w * 512]);
            load_lds16(Wt + brow0 + kn, &Bs[nxt][w * 512]);
            load_lds16(Wt + brow1 + kn, &Bs[nxt][2048 + w * 512]);
        }

        const _Float16* Ac = As[cur];
        const _Float16* Bc = Bs[cur];
        half8_t af[4], bf[4];
#pragma unroll
        for (int i = 0; i < 4; ++i) {
            af[i] = *(const half8_t*)&Ac[(wm + i * 16 + lrow) * 32 + lk];
            bf[i] = *(const half8_t*)&Bc[(wn + i * 16 + lrow) * 32 + lk];
        }
#pragma unroll
        for (int i = 0; i < 4; ++i)
#pragma unroll
            for (int j = 0; j < 4; ++j)
                acc[i][j] = __builtin_amdgcn_mfma_f32_16x16x32_f16(af[i], bf[j], acc[i][j], 0, 0, 0);

        if (ti + 1 < NT) __syncthreads();
    }

    // epilogue: C/D layout col=lane&15, row=(lane>>4)*4+reg
    const int rquad = (lane >> 4) * 4;
#pragma unroll
    for (int i = 0; i < 4; ++i) {
#pragma unroll
        for (int j = 0; j < 4; ++j) {
            const int col = bn + wn + j * 16 + lrow;
            const float bcol = bias[col];
#pragma unroll
            for (int r = 0; r < 4; ++r) {
                const size_t row = (size_t)(bm + wm + i * 16 + rquad + r);
                float v = acc[i][j][r] + bcol;
                if constexpr (MODE == 1) {
                    v = ((float)attn[row * (size_t)ldc + col] + v) * gamma[col];
                    ((float*)Cv)[row * (size_t)ldc + col] = v;
                } else if constexpr (MODE == 2) {
                    ((_Float16*)Cv)[row * (size_t)ldc + col] = (_Float16)v;
                } else {
                    ((float*)Cv)[row * (size_t)ldc + col] = v;
                }
            }
        }
    }
}

// Single GEMM: N=768 (6 col tiles), 384 blocks, XCD-swizzled.
template <int MODE>
__global__ __launch_bounds__(256) void gemm_mfma(
    const _Float16* __restrict__ A, const _Float16* __restrict__ Wt,
    const float* __restrict__ bias, void* __restrict__ C,
    const _Float16* __restrict__ attn, const float* __restrict__ gamma)
{
    const int bid = blockIdx.x;
    const int swz = (bid & 7) * 48 + (bid >> 3);
    gemm_body<MODE>(A, Wt, bias, C, 768, swz & 63, swz >> 6, attn, gamma);
}

// Dual GEMM: two independent jobs, per-job output mode. Counts divisible by 8.
template <int M0, int M1>
__global__ __launch_bounds__(256) void dual_gemm(
    const _Float16* __restrict__ A0, const _Float16* __restrict__ W0,
    const float* __restrict__ b0, void* __restrict__ C0, int ldc0, int cnt0,
    const _Float16* __restrict__ A1, const _Float16* __restrict__ W1,
    const float* __restrict__ b1, void* __restrict__ C1, int ldc1, int cnt1)
{
    int bid = blockIdx.x;
    if (bid < cnt0) {
        const int q = cnt0 >> 3;
        const int swz = (bid & 7) * q + (bid >> 3);
        gemm_body<M0>(A0, W0, b0, C0, ldc0, swz & 63, swz >> 6, nullptr, nullptr);
    } else {
        bid -= cnt0;
        const int q = cnt1 >> 3;
        const int swz = (bid & 7) * q + (bid >> 3);
        gemm_body<M1>(A1, W1, b1, C1, ldc1, swz & 63, swz >> 6, nullptr, nullptr);
    }
}

// ---------------------------------------------------------------------------
// LayerNorm, wave-per-row, fp16 in -> fp16 out. In-place safe.
// ---------------------------------------------------------------------------
__device__ __forceinline__ void ln_wave_body(
    const _Float16* __restrict__ X, _Float16* __restrict__ A,
    const float* __restrict__ g, const float* __restrict__ beta, int row)
{
    const int lane = threadIdx.x & 63;
    const _Float16* x = X + (size_t)row * D_MODEL;
    float v[12];
    float s = 0.f, s2 = 0.f;
#pragma unroll
    for (int j = 0; j < 12; ++j) {
        v[j] = (float)x[lane + 64 * j];
        s += v[j];
        s2 += v[j] * v[j];
    }
#pragma unroll
    for (int m = 1; m < 64; m <<= 1) {
        s += __shfl_xor(s, m);
        s2 += __shfl_xor(s2, m);
    }
    const float mean = s * (1.f / 768.f);
    const float var = s2 * (1.f / 768.f) - mean * mean;
    const float rstd = rsqrtf(var + 1e-6f);
    _Float16* arow = A + (size_t)row * D_MODEL;
#pragma unroll
    for (int j = 0; j < 12; ++j) {
        const int cc = lane + 64 * j;
        arow[cc] = (_Float16)((v[j] - mean) * rstd * g[cc] + beta[cc]);
    }
}

__global__ __launch_bounds__(256) void ln2_wave(
    const _Float16* __restrict__ X0, _Float16* __restrict__ A0,
    const float* __restrict__ g0, const float* __restrict__ b0,
    const _Float16* __restrict__ X1, _Float16* __restrict__ A1,
    const float* __restrict__ g1, const float* __restrict__ b1)
{
    const int r = blockIdx.x * 4 + (threadIdx.x >> 6);
    if (r < MTOT) ln_wave_body(X0, A0, g0, b0, r);
    else          ln_wave_body(X1, A1, g1, b1, r - MTOT);
}

__global__ __launch_bounds__(256) void ln_wave(
    const _Float16* __restrict__ X, _Float16* __restrict__ A,
    const float* __restrict__ g, const float* __restrict__ beta)
{
    const int r = blockIdx.x * 4 + (threadIdx.x >> 6);
    ln_wave_body(X, A, g, beta, r);
}

// ---------------------------------------------------------------------------
// Merged conversions: [0,12288) act fp32->fp16; [12288,15744) weight transpose
// fp32->fp16; [15744,16128) combined offset|aw weights + bias.
// ---------------------------------------------------------------------------
__global__ __launch_bounds__(256) void convert_all(
    const float* __restrict__ query, _Float16* __restrict__ actA,
    const float* __restrict__ feat, _Float16* __restrict__ actB,
    const float* __restrict__ w0, const float* __restrict__ w1,
    const float* __restrict__ w2, const float* __restrict__ w3,
    const float* __restrict__ w4, const float* __restrict__ w5,
    _Float16* __restrict__ Wall,
    const float* __restrict__ Woff_c, const float* __restrict__ Wa_c,
    const float* __restrict__ boff_c, const float* __restrict__ ba_c,
    const float* __restrict__ Woff_s, const float* __restrict__ Wa_s,
    const float* __restrict__ boff_s, const float* __restrict__ ba_s,
    _Float16* __restrict__ Wc, _Float16* __restrict__ Ws,
    float* __restrict__ bias_c, float* __restrict__ bias_s)
{
    __shared__ float tile[32][33];
    const int bid = blockIdx.x;
    const int t = threadIdx.x;

    if (bid < 12288) {
        const int i = bid * 256 + t;
        const int sel = i / (MTOT * 192);
        const int r = i - sel * (MTOT * 192);
        const float* X = sel ? feat : query;
        _Float16* D = sel ? actB : actA;
        const int c4 = r * 4;
        const float4 v = *(const float4*)(X + (size_t)c4);
        _Float16 o[4] = {(_Float16)v.x, (_Float16)v.y, (_Float16)v.z, (_Float16)v.w};
        *(uint2*)(D + (size_t)c4) = *(uint2*)o;
    } else if (bid < 15744) {
        const int g = bid - 12288;
        const int wi = g / 576;
        const int gx = g - wi * 576;
        const float* W = (wi == 0) ? w0 : (wi == 1) ? w1 : (wi == 2) ? w2
                       : (wi == 3) ? w3 : (wi == 4) ? w4 : w5;
        _Float16* Wt = Wall + (size_t)wi * 768 * 768;
        const int tk0 = (gx / 24) * 32;
        const int tn0 = (gx % 24) * 32;
#pragma unroll
        for (int r = 0; r < 4; ++r) {
            const int row = r * 8 + (t >> 5);
            const int col = t & 31;
            tile[row][col] = W[(size_t)(tk0 + row) * 768 + tn0 + col];
        }
        __syncthreads();
        const int n = t >> 3;
        const int kq = (t & 7) * 4;
        _Float16* dst = Wt + (size_t)(tn0 + n) * 768 + tk0 + kq;
#pragma unroll
        for (int u = 0; u < 4; ++u) dst[u] = (_Float16)tile[kq + u][n];
    } else {
        const int i = (bid - 15744) * 256 + t;
        if (i >= 2 * 256 * 192) return;
        const int pair = i / (256 * 192);
        const int r = i - pair * (256 * 192);
        const int n = r / 192;
        const int k0 = (r - n * 192) * 4;
        const float* Woff = pair ? Woff_s : Woff_c;
        const float* Wa = pair ? Wa_s : Wa_c;
        _Float16* dst = pair ? Ws : Wc;
        _Float16* row = dst + (size_t)n * 768;
#pragma unroll
        for (int u = 0; u < 4; ++u) {
            const int k = k0 + u;
            float v = (n < 128) ? Woff[(size_t)k * 128 + n]
                    : (n < 192) ? Wa[(size_t)k * 64 + (n - 128)] : 0.f;
            row[k] = (_Float16)v;
        }
        if (k0 == 0) {
            const float* boff = pair ? boff_s : boff_c;
            const float* ba = pair ? ba_s : ba_c;
            float* bias = pair ? bias_s : bias_c;
            bias[n] = (n < 128) ? boff[n] : (n < 192) ? ba[n - 128] : 0.f;
        }
    }
}

// ---------------------------------------------------------------------------
// Fused softmax/loc + bilinear sampling. 192-thread blocks, each covers 2 bq.
// Threads 0..31 compute loc/aw for the block's 32 (bq,h) into LDS; then all
// 192 threads sample: thread -> (lbqh = tid/6, c = tid%6), d0 = 8c, fp16 val.
// XCD-chunk swizzle over 4096 blocks.
// ---------------------------------------------------------------------------
__global__ __launch_bounds__(192) void sample_fused(
    const _Float16* __restrict__ value, const float* __restrict__ offc,
    _Float16* __restrict__ A)
{
    __shared__ float loc_s[32][8];
    __shared__ float aw_s[32][4];

    const int bid = blockIdx.x;                    // 4096 = 8 * 512
    const int swz = (bid & 7) * 512 + (bid >> 3);  // XCD-chunk swizzle
    const int bq_base = swz * 2;
    const int t = threadIdx.x;

    if (t < 32) {
        const int bq = bq_base + (t >> 4);
        const int h = t & 15;
        const int q = bq & (LQ - 1);
        const float* orow = offc + (size_t)bq * 256 + h * 8;
        const float* arow = offc + (size_t)bq * 256 + 128 + h * 4;
        float a0 = arow[0], a1 = arow[1], a2 = arow[2], a3 = arow[3];
        float mx = fmaxf(fmaxf(a0, a1), fmaxf(a2, a3));
        float e0 = expf(a0 - mx), e1 = expf(a1 - mx), e2 = expf(a2 - mx), e3 = expf(a3 - mx);
        float r = 1.f / (e0 + e1 + e2 + e3);
        const float refx = ((q & 63) + 0.5f) * (1.f / 64.f);
        const float refy = ((q >> 6) + 0.5f) * (1.f / 64.f);
#pragma unroll
        for (int p = 0; p < 4; ++p) {
            loc_s[t][p * 2 + 0] = refx + orow[p * 2 + 0] * (1.f / 64.f);
            loc_s[t][p * 2 + 1] = refy + orow[p * 2 + 1] * (1.f / 64.f);
        }
        aw_s[t][0] = e0 * r; aw_s[t][1] = e1 * r;
        aw_s[t][2] = e2 * r; aw_s[t][3] = e3 * r;
    }
    __syncthreads();

    const int lbqh = t / 6;
    const int c = t - lbqh * 6;
    const int d0 = c * 8;
    const int bq = bq_base + (lbqh >> 4);
    const int h = lbqh & 15;
    const int b = bq >> 12;

    const _Float16* vbase = value + (size_t)b * LQ * D_MODEL + h * DH + d0;

    float acc[8] = {};
#pragma unroll
    for (int p = 0; p < 4; ++p) {
        const float x = loc_s[lbqh][p * 2 + 0] * 64.f - 0.5f;
        const float y = loc_s[lbqh][p * 2 + 1] * 64.f - 0.5f;
        const float xf = floorf(x), yf = floorf(y);
        const float wx1 = x - xf, wy1 = y - yf;
        const float wx0 = 1.f - wx1, wy0 = 1.f - wy1;
        const int x0 = (int)xf, y0 = (int)yf;
        const int x1 = x0 + 1, y1 = y0 + 1;
        const float wp = aw_s[lbqh][p];
        const bool vx0 = (x0 >= 0) && (x0 < 64);
        const bool vx1 = (x1 >= 0) && (x1 < 64);
        const bool vy0 = (y0 >= 0) && (y0 < 64);
        const bool vy1 = (y1 >= 0) && (y1 < 64);
        const float cw[4] = {wp * wx0 * wy0, wp * wx1 * wy0, wp * wx0 * wy1, wp * wx1 * wy1};
        const bool cv[4] = {vx0 && vy0, vx1 && vy0, vx0 && vy1, vx1 && vy1};
        const int cxy[4][2] = {{x0, y0}, {x1, y0}, {x0, y1}, {x1, y1}};
#pragma unroll
        for (int k = 0; k < 4; ++k) {
            if (cv[k]) {
                const half8_t g = *(const half8_t*)(vbase + (size_t)(cxy[k][1] * 64 + cxy[k][0]) * D_MODEL);
#pragma unroll
                for (int u = 0; u < 8; ++u) acc[u] += cw[k] * (float)g[u];
            }
        }
    }

    _Float16* arow = A + (size_t)bq * D_MODEL + h * DH + d0;
    _Float16 o[8];
#pragma unroll
    for (int u = 0; u < 8; ++u) o[u] = (_Float16)acc[u];
    *(uint4*)arow = *(uint4*)o;
}

// ---------------------------------------------------------------------------
extern "C" void kernel_launch(void* const* d_in, const int* in_sizes, int n_in,
                              void* d_out, int out_size, void* d_ws, size_t ws_size,
                              hipStream_t stream)
{
    const float* query   = (const float*)d_in[0];
    const float* feat    = (const float*)d_in[1];
    const float* qn_W    = (const float*)d_in[4];
    const float* qn_b    = (const float*)d_in[5];
    const float* qn_g    = (const float*)d_in[6];
    const float* qn_beta = (const float*)d_in[7];
    const float* fn_W    = (const float*)d_in[8];
    const float* fn_b    = (const float*)d_in[9];
    const float* fn_g    = (const float*)d_in[10];
    const float* fn_beta = (const float*)d_in[11];
    const float* nm_g    = (const float*)d_in[12];
    const float* nm_beta = (const float*)d_in[13];
    const float* gamma1  = (const float*)d_in[14];
    const float* c_Wv    = (const float*)d_in[15];
    const float* c_bv    = (const float*)d_in[16];
    const float* c_Woff  = (const float*)d_in[17];
    const float* c_boff  = (const float*)d_in[18];
    const float* c_Wa    = (const float*)d_in[19];
    const float* c_ba    = (const float*)d_in[20];
    const float* c_Wo    = (const float*)d_in[21];
    const float* c_bo    = (const float*)d_in[22];
    const float* s_Wv    = (const float*)d_in[23];
    const float* s_bv    = (const float*)d_in[24];
    const float* s_Woff  = (const float*)d_in[25];
    const float* s_boff  = (const float*)d_in[26];
    const float* s_Wa    = (const float*)d_in[27];
    const float* s_ba    = (const float*)d_in[28];
    const float* s_Wo    = (const float*)d_in[29];
    const float* s_bo    = (const float*)d_in[30];

    const size_t SZ = (size_t)MTOT * D_MODEL;  // 6291456 elements
    _Float16* hA    = (_Float16*)d_ws;         // query16 -> attn16
    _Float16* hB    = hA + SZ;                 // feat16 -> samp16
    _Float16* hQ    = hB + SZ;                 // qn_raw->qn16 -> attn1n16
    _Float16* hF    = hQ + SZ;                 // fn_raw->fn16
    _Float16* val16 = hF + SZ;                 // value fp16
    float* offc   = (float*)(val16 + SZ);      // M x 256 fp32
    float* bias_c = offc + (size_t)MTOT * 256;
    float* bias_s = bias_c + 256;
    _Float16* W6 = (_Float16*)(bias_s + 256);  // 6 x 768 x 768 fp16
    _Float16* W_qn  = W6 + (size_t)0 * 768 * 768;
    _Float16* W_fn  = W6 + (size_t)1 * 768 * 768;
    _Float16* W_cWv = W6 + (size_t)2 * 768 * 768;
    _Float16* W_cWo = W6 + (size_t)3 * 768 * 768;
    _Float16* W_sWv = W6 + (size_t)4 * 768 * 768;
    _Float16* W_sWo = W6 + (size_t)5 * 768 * 768;
    _Float16* Woffa_c = W6 + (size_t)6 * 768 * 768;  // 256 x 768
    _Float16* Woffa_s = Woffa_c + (size_t)256 * 768;

    float* out = (float*)d_out;
    const dim3 blk(256);

    // ---- all conversions in one dispatch ----
    convert_all<<<16128, blk, 0, stream>>>(
        query, hA, feat, hB,
        qn_W, fn_W, c_Wv, c_Wo, s_Wv, s_Wo, W6,
        c_Woff, c_Wa, c_boff, c_ba, s_Woff, s_Wa, s_boff, s_ba,
        Woffa_c, Woffa_s, bias_c, bias_s);

    // ---- cross attention ----
    dual_gemm<2, 2><<<768, blk, 0, stream>>>(hA, W_qn, qn_b, hQ, 768, 384,
                                             hB, W_fn, fn_b, hF, 768, 384);
    ln2_wave<<<2 * MTOT / 4, blk, 0, stream>>>(hQ, hQ, qn_g, qn_beta,
                                               hF, hF, fn_g, fn_beta);
    dual_gemm<2, 0><<<512, blk, 0, stream>>>(hF, W_cWv, c_bv, val16, 768, 384,
                                             hQ, Woffa_c, bias_c, offc, 256, 128);
    sample_fused<<<4096, dim3(192), 0, stream>>>(val16, offc, hB);
    gemm_mfma<2><<<384, blk, 0, stream>>>(hB, W_cWo, c_bo, hA, nullptr, nullptr);  // attn16 -> hA

    // ---- self attention ----
    ln_wave<<<MTOT / 4, blk, 0, stream>>>(hA, hQ, nm_g, nm_beta);  // attn1 -> hQ
    dual_gemm<2, 0><<<512, blk, 0, stream>>>(hQ, W_sWv, s_bv, val16, 768, 384,
                                             hQ, Woffa_s, bias_s, offc, 256, 128);
    sample_fused<<<4096, dim3(192), 0, stream>>>(val16, offc, hB);
    // final: out = gamma1 * (attn16 + samp@s_Wo + s_bo)
    gemm_mfma<1><<<384, blk, 0, stream>>>(hB, W_sWo, s_bo, out, hA, gamma1);
}